// Round 1
// baseline (161.565 us; speedup 1.0000x reference)
//
#include <hip/hip_runtime.h>
#include <math.h>

// Gaussian splatting forward renderer, MI355X.
// N=8192 gaussians, 128x128 image, 64 tiles of 16x16.
// Kernel 1: per-gaussian preprocess -> packed float4 params in d_ws.
// Kernel 2: one block per tile; build candidate list (bbox test), bitonic-sort
//           (depth_bits, idx) keys in LDS (== stable argsort restricted to
//           survivors), then front-to-back blend staged through LDS chunks.

#define NMAX 8192
#define TPB 256

__global__ void gs_preprocess(
    const float* __restrict__ means3D, const float* __restrict__ opacity,
    const float* __restrict__ scales, const float* __restrict__ rotations,
    const float* __restrict__ shs, const float* __restrict__ viewmatrix,
    const float* __restrict__ projmatrix, const float* __restrict__ camcenter,
    float4* __restrict__ A, float4* __restrict__ B, float4* __restrict__ C,
    float4* __restrict__ D, unsigned* __restrict__ K, int N)
{
    int i = blockIdx.x * blockDim.x + threadIdx.x;
    if (i >= N) return;

    float V[16], P[16];
#pragma unroll
    for (int k = 0; k < 16; ++k) V[k] = viewmatrix[k];
#pragma unroll
    for (int k = 0; k < 16; ++k) P[k] = projmatrix[k];

    float mx = means3D[3*i+0], my = means3D[3*i+1], mz = means3D[3*i+2];

    // row-vector [m,1] times 4x4 matrices
    float pv0 = mx*V[0] + my*V[4] + mz*V[8]  + V[12];
    float pv1 = mx*V[1] + my*V[5] + mz*V[9]  + V[13];
    float pv2 = mx*V[2] + my*V[6] + mz*V[10] + V[14];
    float pv3 = mx*V[3] + my*V[7] + mz*V[11] + V[15];

    float ph0 = pv0*P[0] + pv1*P[4] + pv2*P[8]  + pv3*P[12];
    float ph1 = pv0*P[1] + pv1*P[5] + pv2*P[9]  + pv3*P[13];
    float ph3 = pv0*P[3] + pv1*P[7] + pv2*P[11] + pv3*P[15];
    float invw = 1.0f / (ph3 + 1e-6f);
    float ppx = ph0 * invw, ppy = ph1 * invw;
    float depth = pv2;

    // ---- SH (degree 3), dirs = means3D - camera_center (UNNORMALIZED, per ref)
    float rdx = mx - camcenter[0], rdy = my - camcenter[1], rdz = mz - camcenter[2];
    float xx = rdx*rdx, yy = rdy*rdy, zz = rdz*rdz;
    float xy = rdx*rdy, yz = rdy*rdz, xz = rdx*rdz;
    const float C0 = 0.28209479177387814f;
    const float C1 = 0.4886025119029199f;
    const float C2_0 =  1.0925484305920792f, C2_1 = -1.0925484305920792f,
                C2_2 =  0.31539156525252005f, C2_3 = -1.0925484305920792f,
                C2_4 =  0.5462742152960396f;
    const float C3_0 = -0.5900435899266435f, C3_1 = 2.890611442640554f,
                C3_2 = -0.4570457994644658f, C3_3 = 0.3731763325901154f,
                C3_4 = -0.4570457994644658f, C3_5 = 1.445305721320277f,
                C3_6 = -0.5900435899266435f;
    float col[3];
#pragma unroll
    for (int c = 0; c < 3; ++c) {
        const float* sh = shs + (size_t)i*48 + c;  // coeff k at sh[3*k]
        float res = C0*sh[0]
            - C1*rdy*sh[3] + C1*rdz*sh[6] - C1*rdx*sh[9]
            + C2_0*xy*sh[12] + C2_1*yz*sh[15] + C2_2*(2.f*zz-xx-yy)*sh[18]
            + C2_3*xz*sh[21] + C2_4*(xx-yy)*sh[24]
            + C3_0*rdy*(3.f*xx-yy)*sh[27] + C3_1*xy*rdz*sh[30]
            + C3_2*rdy*(4.f*zz-xx-yy)*sh[33] + C3_3*rdz*(2.f*zz-3.f*xx-3.f*yy)*sh[36]
            + C3_4*rdx*(4.f*zz-xx-yy)*sh[39] + C3_5*rdz*(xx-yy)*sh[42]
            + C3_6*rdx*(xx-3.f*yy)*sh[45];
        col[c] = fmaxf(res + 0.5f, 0.0f);
    }

    // ---- cov3d = (R*diag(s)) (R*diag(s))^T
    float qr = rotations[4*i+0], qx = rotations[4*i+1], qy = rotations[4*i+2], qz = rotations[4*i+3];
    float qn = sqrtf(qr*qr + qx*qx + qy*qy + qz*qz);
    qr /= qn; qx /= qn; qy /= qn; qz /= qn;
    float R00 = 1.f - 2.f*(qy*qy + qz*qz), R01 = 2.f*(qx*qy - qr*qz), R02 = 2.f*(qx*qz + qr*qy);
    float R10 = 2.f*(qx*qy + qr*qz), R11 = 1.f - 2.f*(qx*qx + qz*qz), R12 = 2.f*(qy*qz - qr*qx);
    float R20 = 2.f*(qx*qz - qr*qy), R21 = 2.f*(qy*qz + qr*qx), R22 = 1.f - 2.f*(qx*qx + qy*qy);
    float s0 = scales[3*i+0], s1 = scales[3*i+1], s2 = scales[3*i+2];
    float L00=R00*s0, L01=R01*s1, L02=R02*s2;
    float L10=R10*s0, L11=R11*s1, L12=R12*s2;
    float L20=R20*s0, L21=R21*s1, L22=R22*s2;
    float c3[3][3];
    c3[0][0]=L00*L00+L01*L01+L02*L02;
    c3[0][1]=L00*L10+L01*L11+L02*L12;
    c3[0][2]=L00*L20+L01*L21+L02*L22;
    c3[1][1]=L10*L10+L11*L11+L12*L12;
    c3[1][2]=L10*L20+L11*L21+L12*L22;
    c3[2][2]=L20*L20+L21*L21+L22*L22;
    c3[1][0]=c3[0][1]; c3[2][0]=c3[0][2]; c3[2][1]=c3[1][2];

    // ---- EWA projection
    const float TANX = 0.5773502691896257f;  // tan(pi/6)
    const float FX = 128.0f / (2.0f * TANX);
    const float FY = FX;
    float tz = pv2;
    float limx = 1.3f * TANX;
    float txv = fminf(fmaxf(pv0 / tz, -limx), limx) * tz;
    float tyv = fminf(fmaxf(pv1 / tz, -limx), limx) * tz;
    float j00 = FX / tz, j02 = -txv * FX / (tz*tz);
    float j11 = FY / tz, j12 = -tyv * FY / (tz*tz);

    // Wm = V[:3,:3]^T -> Wm[r][c] = V[c*4+r]
    float Wm[3][3];
    Wm[0][0]=V[0]; Wm[0][1]=V[4]; Wm[0][2]=V[8];
    Wm[1][0]=V[1]; Wm[1][1]=V[5]; Wm[1][2]=V[9];
    Wm[2][0]=V[2]; Wm[2][1]=V[6]; Wm[2][2]=V[10];
    float tmp[3][3], M[3][3];
#pragma unroll
    for (int r = 0; r < 3; ++r)
#pragma unroll
        for (int c = 0; c < 3; ++c)
            tmp[r][c] = Wm[r][0]*c3[0][c] + Wm[r][1]*c3[1][c] + Wm[r][2]*c3[2][c];
#pragma unroll
    for (int r = 0; r < 3; ++r)
#pragma unroll
        for (int c = 0; c < 3; ++c)
            M[r][c] = tmp[r][0]*Wm[c][0] + tmp[r][1]*Wm[c][1] + tmp[r][2]*Wm[c][2];

    // cov2d = (J M J^T)[:2,:2] + 0.3 I   (J rows: [j00,0,j02],[0,j11,j12])
    float JM00 = j00*M[0][0] + j02*M[2][0];
    float JM01 = j00*M[0][1] + j02*M[2][1];
    float JM02 = j00*M[0][2] + j02*M[2][2];
    float JM11 = j11*M[1][1] + j12*M[2][1];
    float JM12 = j11*M[1][2] + j12*M[2][2];
    float a = JM00*j00 + JM02*j02 + 0.3f;   // cov00
    float b = JM01*j11 + JM02*j12;          // cov01 (== cov10 up to fp)
    float d = JM11*j11 + JM12*j12 + 0.3f;   // cov11

    float m2x = ((ppx + 1.0f)*128.0f - 1.0f)*0.5f;
    float m2y = ((ppy + 1.0f)*128.0f - 1.0f)*0.5f;

    float det = a*d - b*b;
    float mid = 0.5f*(a + d);
    float sq = sqrtf(fmaxf(mid*mid - det, 0.1f));
    float lam1 = mid + sq, lam2 = mid - sq;
    float radii = 3.0f * ceilf(sqrtf(fmaxf(lam1, lam2)));
    float rminx = fminf(fmaxf(m2x - radii, 0.0f), 127.0f);
    float rminy = fminf(fmaxf(m2y - radii, 0.0f), 127.0f);
    float rmaxx = fminf(fmaxf(m2x + radii, 0.0f), 127.0f);
    float rmaxy = fminf(fmaxf(m2y + radii, 0.0f), 127.0f);

    float idet = 1.0f / det;
    float c00i = d*idet, c11i = a*idet, cxyi = -2.0f*b*idet;

    // monotone key for positive/negative float depth; stable tie-break by idx
    unsigned kb = __float_as_uint(depth);
    kb = (kb & 0x80000000u) ? ~kb : (kb | 0x80000000u);

    K[i] = kb;
    A[i] = make_float4(m2x, m2y, c00i, c11i);
    B[i] = make_float4(cxyi, opacity[i], depth, 0.0f);
    C[i] = make_float4(col[0], col[1], col[2], 0.0f);
    D[i] = make_float4(rminx, rminy, rmaxx, rmaxy);
}

__global__ __launch_bounds__(TPB) void gs_render(
    const float4* __restrict__ A, const float4* __restrict__ B,
    const float4* __restrict__ C, const float4* __restrict__ D,
    const unsigned* __restrict__ K, float* __restrict__ out, int N)
{
    __shared__ unsigned long long s_keys[NMAX];   // 64 KiB
    __shared__ int s_count;
    __shared__ float4 sA[TPB], sB[TPB], sC[TPB];  // 12 KiB

    const int tid = threadIdx.x;
    const int tile = blockIdx.x;
    const int h = (tile >> 3) * 16;   // 8 tiles per row
    const int w = (tile & 7) * 16;

    if (tid == 0) s_count = 0;
    __syncthreads();

    const float fw = (float)w, fh = (float)h;
    // Phase 1: candidate list (order fixed later by unique composite keys)
    for (int g = tid; g < N; g += TPB) {
        float4 d4 = D[g];
        float tlx = fmaxf(d4.x, fw), tly = fmaxf(d4.y, fh);
        float brx = fminf(d4.z, fw + 15.0f), bry = fminf(d4.w, fh + 15.0f);
        if (brx > tlx && bry > tly) {
            int pos = atomicAdd(&s_count, 1);
            s_keys[pos] = (((unsigned long long)K[g]) << 32) | (unsigned)g;
        }
    }
    __syncthreads();
    const int count = s_count;

    // Phase 2: bitonic sort on padded pow2
    int n = 2;
    while (n < count) n <<= 1;
    for (int i2 = count + tid; i2 < n; i2 += TPB) s_keys[i2] = ~0ULL;
    __syncthreads();
    for (int k = 2; k <= n; k <<= 1) {
        for (int j = k >> 1; j > 0; j >>= 1) {
            for (int i = tid; i < n; i += TPB) {
                int ixj = i ^ j;
                if (ixj > i) {
                    unsigned long long va = s_keys[i], vb = s_keys[ixj];
                    bool up = ((i & k) == 0);
                    if ((va > vb) == up) { s_keys[i] = vb; s_keys[ixj] = va; }
                }
            }
            __syncthreads();
        }
    }

    // Phase 3: front-to-back blend, LDS-staged in chunks of TPB
    const int pxi = tid & 15, pyi = tid >> 4;
    const float px = (float)(w + pxi), py = (float)(h + pyi);
    float T = 1.0f, cr = 0.f, cg = 0.f, cb = 0.f, dp = 0.f, ac = 0.f;

    for (int base = 0; base < count; base += TPB) {
        int m = min(TPB, count - base);
        __syncthreads();
        if (tid < m) {
            int g = (int)(s_keys[base + tid] & 0xffffffffu);
            sA[tid] = A[g]; sB[tid] = B[g]; sC[tid] = C[g];
        }
        __syncthreads();
        for (int jj = 0; jj < m; ++jj) {
            float4 a4 = sA[jj], b4 = sB[jj], c4 = sC[jj];
            float ddx = px - a4.x, ddy = py - a4.y;
            float power = -0.5f * (ddx*ddx*a4.z + ddy*ddy*a4.w + ddx*ddy*b4.x);
            float alpha = fminf(expf(power) * b4.y, 0.99f);
            float wgt = alpha * T;
            cr += wgt * c4.x; cg += wgt * c4.y; cb += wgt * c4.z;
            dp += wgt * b4.z; ac += wgt;
            T *= (1.0f - alpha);
        }
    }

    // white background
    cr += (1.0f - ac); cg += (1.0f - ac); cb += (1.0f - ac);

    const int y = h + pyi, x = w + pxi;
    const int pix = y * 128 + x;
    out[pix*3 + 0] = cr;
    out[pix*3 + 1] = cg;
    out[pix*3 + 2] = cb;
    out[128*128*3 + pix] = dp;
    out[128*128*3 + 128*128 + pix] = ac;
}

extern "C" void kernel_launch(void* const* d_in, const int* in_sizes, int n_in,
                              void* d_out, int out_size, void* d_ws, size_t ws_size,
                              hipStream_t stream) {
    const float* means3D    = (const float*)d_in[0];
    const float* opacity    = (const float*)d_in[1];
    const float* scales     = (const float*)d_in[2];
    const float* rotations  = (const float*)d_in[3];
    const float* shs        = (const float*)d_in[4];
    const float* viewmatrix = (const float*)d_in[5];
    const float* projmatrix = (const float*)d_in[6];
    const float* camcenter  = (const float*)d_in[7];
    float* out = (float*)d_out;

    int N = in_sizes[0] / 3;   // 8192

    float4* A = (float4*)d_ws;
    float4* B = A + N;
    float4* C = B + N;
    float4* D = C + N;
    unsigned* K = (unsigned*)(D + N);

    gs_preprocess<<<(N + TPB - 1) / TPB, TPB, 0, stream>>>(
        means3D, opacity, scales, rotations, shs, viewmatrix, projmatrix,
        camcenter, A, B, C, D, K, N);

    gs_render<<<64, TPB, 0, stream>>>(A, B, C, D, K, out, N);
}

// Round 2
// 58.885 us; speedup vs baseline: 2.7437x; 2.7437x over previous
//
#include <hip/hip_runtime.h>
#include <math.h>

// Gaussian splatting forward renderer, MI355X.
// R1: depth-segmented parallel blend.
//  K1 gs_preprocess     : per-gaussian params -> ws
//  K2 gs_tile_sort      : 64 blocks x 1024 thr; bbox filter + bitonic sort
//                         (depth_key<<32|idx) in LDS -> sorted idx lists
//  K3 gs_render_partial : 64 tiles x 16 segments blocks x 256 thr; each block
//                         blends its depth-segment into per-pixel partials
//                         {rgb,dep,acc,T} (exact up to fp reassociation)
//  K4 gs_combine        : ordered prefix-combine of segments + white bkgd

#define NMAX 8192
#define TPB 256
#define SORT_TPB 1024
#define NSEG 16

__global__ void gs_preprocess(
    const float* __restrict__ means3D, const float* __restrict__ opacity,
    const float* __restrict__ scales, const float* __restrict__ rotations,
    const float* __restrict__ shs, const float* __restrict__ viewmatrix,
    const float* __restrict__ projmatrix, const float* __restrict__ camcenter,
    float4* __restrict__ A, float4* __restrict__ B, float4* __restrict__ C,
    float4* __restrict__ D, unsigned* __restrict__ K, int N)
{
    int i = blockIdx.x * blockDim.x + threadIdx.x;
    if (i >= N) return;

    float V[16], P[16];
#pragma unroll
    for (int k = 0; k < 16; ++k) V[k] = viewmatrix[k];
#pragma unroll
    for (int k = 0; k < 16; ++k) P[k] = projmatrix[k];

    float mx = means3D[3*i+0], my = means3D[3*i+1], mz = means3D[3*i+2];

    float pv0 = mx*V[0] + my*V[4] + mz*V[8]  + V[12];
    float pv1 = mx*V[1] + my*V[5] + mz*V[9]  + V[13];
    float pv2 = mx*V[2] + my*V[6] + mz*V[10] + V[14];
    float pv3 = mx*V[3] + my*V[7] + mz*V[11] + V[15];

    float ph0 = pv0*P[0] + pv1*P[4] + pv2*P[8]  + pv3*P[12];
    float ph1 = pv0*P[1] + pv1*P[5] + pv2*P[9]  + pv3*P[13];
    float ph3 = pv0*P[3] + pv1*P[7] + pv2*P[11] + pv3*P[15];
    float invw = 1.0f / (ph3 + 1e-6f);
    float ppx = ph0 * invw, ppy = ph1 * invw;
    float depth = pv2;

    // SH deg 3, dirs = means3D - camera_center (unnormalized, per ref)
    float rdx = mx - camcenter[0], rdy = my - camcenter[1], rdz = mz - camcenter[2];
    float xx = rdx*rdx, yy = rdy*rdy, zz = rdz*rdz;
    float xy = rdx*rdy, yz = rdy*rdz, xz = rdx*rdz;
    const float C0 = 0.28209479177387814f;
    const float C1 = 0.4886025119029199f;
    const float C2_0 =  1.0925484305920792f, C2_1 = -1.0925484305920792f,
                C2_2 =  0.31539156525252005f, C2_3 = -1.0925484305920792f,
                C2_4 =  0.5462742152960396f;
    const float C3_0 = -0.5900435899266435f, C3_1 = 2.890611442640554f,
                C3_2 = -0.4570457994644658f, C3_3 = 0.3731763325901154f,
                C3_4 = -0.4570457994644658f, C3_5 = 1.445305721320277f,
                C3_6 = -0.5900435899266435f;
    float col[3];
#pragma unroll
    for (int c = 0; c < 3; ++c) {
        const float* sh = shs + (size_t)i*48 + c;
        float res = C0*sh[0]
            - C1*rdy*sh[3] + C1*rdz*sh[6] - C1*rdx*sh[9]
            + C2_0*xy*sh[12] + C2_1*yz*sh[15] + C2_2*(2.f*zz-xx-yy)*sh[18]
            + C2_3*xz*sh[21] + C2_4*(xx-yy)*sh[24]
            + C3_0*rdy*(3.f*xx-yy)*sh[27] + C3_1*xy*rdz*sh[30]
            + C3_2*rdy*(4.f*zz-xx-yy)*sh[33] + C3_3*rdz*(2.f*zz-3.f*xx-3.f*yy)*sh[36]
            + C3_4*rdx*(4.f*zz-xx-yy)*sh[39] + C3_5*rdz*(xx-yy)*sh[42]
            + C3_6*rdx*(xx-3.f*yy)*sh[45];
        col[c] = fmaxf(res + 0.5f, 0.0f);
    }

    // cov3d
    float qr = rotations[4*i+0], qx = rotations[4*i+1], qy = rotations[4*i+2], qz = rotations[4*i+3];
    float qn = sqrtf(qr*qr + qx*qx + qy*qy + qz*qz);
    qr /= qn; qx /= qn; qy /= qn; qz /= qn;
    float R00 = 1.f - 2.f*(qy*qy + qz*qz), R01 = 2.f*(qx*qy - qr*qz), R02 = 2.f*(qx*qz + qr*qy);
    float R10 = 2.f*(qx*qy + qr*qz), R11 = 1.f - 2.f*(qx*qx + qz*qz), R12 = 2.f*(qy*qz - qr*qx);
    float R20 = 2.f*(qx*qz - qr*qy), R21 = 2.f*(qy*qz + qr*qx), R22 = 1.f - 2.f*(qx*qx + qy*qy);
    float s0 = scales[3*i+0], s1 = scales[3*i+1], s2 = scales[3*i+2];
    float L00=R00*s0, L01=R01*s1, L02=R02*s2;
    float L10=R10*s0, L11=R11*s1, L12=R12*s2;
    float L20=R20*s0, L21=R21*s1, L22=R22*s2;
    float c3[3][3];
    c3[0][0]=L00*L00+L01*L01+L02*L02;
    c3[0][1]=L00*L10+L01*L11+L02*L12;
    c3[0][2]=L00*L20+L01*L21+L02*L22;
    c3[1][1]=L10*L10+L11*L11+L12*L12;
    c3[1][2]=L10*L20+L11*L21+L12*L22;
    c3[2][2]=L20*L20+L21*L21+L22*L22;
    c3[1][0]=c3[0][1]; c3[2][0]=c3[0][2]; c3[2][1]=c3[1][2];

    // EWA projection
    const float TANX = 0.5773502691896257f;
    const float FX = 128.0f / (2.0f * TANX);
    const float FY = FX;
    float tz = pv2;
    float limx = 1.3f * TANX;
    float txv = fminf(fmaxf(pv0 / tz, -limx), limx) * tz;
    float tyv = fminf(fmaxf(pv1 / tz, -limx), limx) * tz;
    float j00 = FX / tz, j02 = -txv * FX / (tz*tz);
    float j11 = FY / tz, j12 = -tyv * FY / (tz*tz);

    float Wm[3][3];
    Wm[0][0]=V[0]; Wm[0][1]=V[4]; Wm[0][2]=V[8];
    Wm[1][0]=V[1]; Wm[1][1]=V[5]; Wm[1][2]=V[9];
    Wm[2][0]=V[2]; Wm[2][1]=V[6]; Wm[2][2]=V[10];
    float tmp[3][3], M[3][3];
#pragma unroll
    for (int r = 0; r < 3; ++r)
#pragma unroll
        for (int c = 0; c < 3; ++c)
            tmp[r][c] = Wm[r][0]*c3[0][c] + Wm[r][1]*c3[1][c] + Wm[r][2]*c3[2][c];
#pragma unroll
    for (int r = 0; r < 3; ++r)
#pragma unroll
        for (int c = 0; c < 3; ++c)
            M[r][c] = tmp[r][0]*Wm[c][0] + tmp[r][1]*Wm[c][1] + tmp[r][2]*Wm[c][2];

    float JM00 = j00*M[0][0] + j02*M[2][0];
    float JM01 = j00*M[0][1] + j02*M[2][1];
    float JM02 = j00*M[0][2] + j02*M[2][2];
    float JM11 = j11*M[1][1] + j12*M[2][1];
    float JM12 = j11*M[1][2] + j12*M[2][2];
    float a = JM00*j00 + JM02*j02 + 0.3f;
    float b = JM01*j11 + JM02*j12;
    float d = JM11*j11 + JM12*j12 + 0.3f;

    float m2x = ((ppx + 1.0f)*128.0f - 1.0f)*0.5f;
    float m2y = ((ppy + 1.0f)*128.0f - 1.0f)*0.5f;

    float det = a*d - b*b;
    float mid = 0.5f*(a + d);
    float sq = sqrtf(fmaxf(mid*mid - det, 0.1f));
    float lam1 = mid + sq, lam2 = mid - sq;
    float radii = 3.0f * ceilf(sqrtf(fmaxf(lam1, lam2)));
    float rminx = fminf(fmaxf(m2x - radii, 0.0f), 127.0f);
    float rminy = fminf(fmaxf(m2y - radii, 0.0f), 127.0f);
    float rmaxx = fminf(fmaxf(m2x + radii, 0.0f), 127.0f);
    float rmaxy = fminf(fmaxf(m2y + radii, 0.0f), 127.0f);

    float idet = 1.0f / det;
    float c00i = d*idet, c11i = a*idet, cxyi = -2.0f*b*idet;

    unsigned kb = __float_as_uint(depth);
    kb = (kb & 0x80000000u) ? ~kb : (kb | 0x80000000u);

    K[i] = kb;
    A[i] = make_float4(m2x, m2y, c00i, c11i);
    B[i] = make_float4(cxyi, opacity[i], depth, 0.0f);
    C[i] = make_float4(col[0], col[1], col[2], 0.0f);
    D[i] = make_float4(rminx, rminy, rmaxx, rmaxy);
}

// 64 blocks (one per tile) x 1024 threads: filter + bitonic sort -> global
__global__ __launch_bounds__(SORT_TPB) void gs_tile_sort(
    const float4* __restrict__ D, const unsigned* __restrict__ K,
    unsigned* __restrict__ sorted, int* __restrict__ counts, int N)
{
    __shared__ unsigned long long s_keys[NMAX];   // 64 KiB
    __shared__ int s_count;

    const int tid = threadIdx.x;
    const int tile = blockIdx.x;
    const int h = (tile >> 3) * 16;
    const int w = (tile & 7) * 16;
    const float fw = (float)w, fh = (float)h;

    if (tid == 0) s_count = 0;
    __syncthreads();

    for (int g = tid; g < N; g += SORT_TPB) {
        float4 d4 = D[g];
        float tlx = fmaxf(d4.x, fw), tly = fmaxf(d4.y, fh);
        float brx = fminf(d4.z, fw + 15.0f), bry = fminf(d4.w, fh + 15.0f);
        if (brx > tlx && bry > tly) {
            int pos = atomicAdd(&s_count, 1);
            s_keys[pos] = (((unsigned long long)K[g]) << 32) | (unsigned)g;
        }
    }
    __syncthreads();
    const int count = s_count;

    if (count > 1) {
        int n = 2;
        while (n < count) n <<= 1;
        for (int i2 = count + tid; i2 < n; i2 += SORT_TPB) s_keys[i2] = ~0ULL;
        __syncthreads();
        for (int k = 2; k <= n; k <<= 1) {
            for (int j = k >> 1; j > 0; j >>= 1) {
                for (int i = tid; i < n; i += SORT_TPB) {
                    int ixj = i ^ j;
                    if (ixj > i) {
                        unsigned long long va = s_keys[i], vb = s_keys[ixj];
                        bool up = ((i & k) == 0);
                        if ((va > vb) == up) { s_keys[i] = vb; s_keys[ixj] = va; }
                    }
                }
                __syncthreads();
            }
        }
    }

    for (int i = tid; i < count; i += SORT_TPB)
        sorted[tile * NMAX + i] = (unsigned)(s_keys[i] & 0xffffffffu);
    if (tid == 0) counts[tile] = count;
}

// grid (NSEG, 64) x 256 thr: blend one depth-segment into per-pixel partials
__global__ __launch_bounds__(TPB) void gs_render_partial(
    const float4* __restrict__ A, const float4* __restrict__ B,
    const float4* __restrict__ C, const unsigned* __restrict__ sorted,
    const int* __restrict__ counts,
    float4* __restrict__ P1, float2* __restrict__ P2)
{
    __shared__ float4 sA[TPB], sB[TPB], sC[TPB];

    const int tid = threadIdx.x;
    const int seg = blockIdx.x;
    const int tile = blockIdx.y;
    const int h = (tile >> 3) * 16;
    const int w = (tile & 7) * 16;

    const int count = counts[tile];
    const int chunk = (count + NSEG - 1) / NSEG;
    const int start = seg * chunk;
    const int end = min(start + chunk, count);

    const int pxi = tid & 15, pyi = tid >> 4;
    const float px = (float)(w + pxi), py = (float)(h + pyi);
    float T = 1.0f, cr = 0.f, cg = 0.f, cb = 0.f, dp = 0.f, ac = 0.f;

    for (int base = start; base < end; base += TPB) {
        int m = min(TPB, end - base);
        __syncthreads();
        if (tid < m) {
            int g = (int)sorted[tile * NMAX + base + tid];
            sA[tid] = A[g]; sB[tid] = B[g]; sC[tid] = C[g];
        }
        __syncthreads();
        for (int jj = 0; jj < m; ++jj) {
            float4 a4 = sA[jj], b4 = sB[jj], c4 = sC[jj];
            float ddx = px - a4.x, ddy = py - a4.y;
            float power = -0.5f * (ddx*ddx*a4.z + ddy*ddy*a4.w + ddx*ddy*b4.x);
            float alpha = fminf(expf(power) * b4.y, 0.99f);
            float wgt = alpha * T;
            cr += wgt * c4.x; cg += wgt * c4.y; cb += wgt * c4.z;
            dp += wgt * b4.z; ac += wgt;
            T *= (1.0f - alpha);
        }
    }

    const int idx = (tile * NSEG + seg) * TPB + tid;
    P1[idx] = make_float4(cr, cg, cb, dp);
    P2[idx] = make_float2(ac, T);
}

// 64 blocks x 256 thr: ordered combine of segments + white background
__global__ __launch_bounds__(TPB) void gs_combine(
    const float4* __restrict__ P1, const float2* __restrict__ P2,
    float* __restrict__ out)
{
    const int tid = threadIdx.x;
    const int tile = blockIdx.x;
    const int h = (tile >> 3) * 16;
    const int w = (tile & 7) * 16;

    float Tpre = 1.0f, cr = 0.f, cg = 0.f, cb = 0.f, dp = 0.f, ac = 0.f;
#pragma unroll
    for (int s = 0; s < NSEG; ++s) {
        const int idx = (tile * NSEG + s) * TPB + tid;
        float4 p1 = P1[idx];
        float2 p2 = P2[idx];
        cr += Tpre * p1.x; cg += Tpre * p1.y; cb += Tpre * p1.z;
        dp += Tpre * p1.w; ac += Tpre * p2.x;
        Tpre *= p2.y;
    }

    cr += (1.0f - ac); cg += (1.0f - ac); cb += (1.0f - ac);

    const int pxi = tid & 15, pyi = tid >> 4;
    const int y = h + pyi, x = w + pxi;
    const int pix = y * 128 + x;
    out[pix*3 + 0] = cr;
    out[pix*3 + 1] = cg;
    out[pix*3 + 2] = cb;
    out[128*128*3 + pix] = dp;
    out[128*128*3 + 128*128 + pix] = ac;
}

extern "C" void kernel_launch(void* const* d_in, const int* in_sizes, int n_in,
                              void* d_out, int out_size, void* d_ws, size_t ws_size,
                              hipStream_t stream) {
    const float* means3D    = (const float*)d_in[0];
    const float* opacity    = (const float*)d_in[1];
    const float* scales     = (const float*)d_in[2];
    const float* rotations  = (const float*)d_in[3];
    const float* shs        = (const float*)d_in[4];
    const float* viewmatrix = (const float*)d_in[5];
    const float* projmatrix = (const float*)d_in[6];
    const float* camcenter  = (const float*)d_in[7];
    float* out = (float*)d_out;

    int N = in_sizes[0] / 3;   // 8192

    // ws layout (16B-aligned blocks first)
    char* p = (char*)d_ws;
    float4* A = (float4*)p;            p += (size_t)NMAX * sizeof(float4);
    float4* B = (float4*)p;            p += (size_t)NMAX * sizeof(float4);
    float4* C = (float4*)p;            p += (size_t)NMAX * sizeof(float4);
    float4* D = (float4*)p;            p += (size_t)NMAX * sizeof(float4);
    float4* P1 = (float4*)p;           p += (size_t)64 * NSEG * TPB * sizeof(float4);
    float2* P2 = (float2*)p;           p += (size_t)64 * NSEG * TPB * sizeof(float2);
    unsigned* K = (unsigned*)p;        p += (size_t)NMAX * sizeof(unsigned);
    unsigned* sorted = (unsigned*)p;   p += (size_t)64 * NMAX * sizeof(unsigned);
    int* counts = (int*)p;             p += 64 * sizeof(int);

    gs_preprocess<<<(N + TPB - 1) / TPB, TPB, 0, stream>>>(
        means3D, opacity, scales, rotations, shs, viewmatrix, projmatrix,
        camcenter, A, B, C, D, K, N);

    gs_tile_sort<<<64, SORT_TPB, 0, stream>>>(D, K, sorted, counts, N);

    gs_render_partial<<<dim3(NSEG, 64), TPB, 0, stream>>>(
        A, B, C, sorted, counts, P1, P2);

    gs_combine<<<64, TPB, 0, stream>>>(P1, P2, out);
}